// Round 2
// baseline (1151.918 us; speedup 1.0000x reference)
//
#include <hip/hip_runtime.h>
#include <hip/hip_bf16.h>
#include <math.h>

#define NTOK 65536
#define DIN 256
#define DOUT 256
#define HID 512
#define NEXP 8
#define NBAND 4
#define RANK 8
#define NFREQ 64
#define CAP 10240
#define LSCALE 2.0f
#define NTILE 16
#define TILES_PER_E (CAP / NTILE)  // 640

__device__ __forceinline__ unsigned key_of(float f) {
    unsigned u = __float_as_uint(f);
    return (u & 0x80000000u) ? ~u : (u | 0x80000000u);
}
__device__ __forceinline__ float inv_key(unsigned k) {
    return (k & 0x80000000u) ? __uint_as_float(k & 0x7FFFFFFFu)
                             : __uint_as_float(~k);
}
__device__ __forceinline__ float gelu_tanh(float v) {
    const float c = 0.7978845608028654f;
    float t = tanhf(c * (v + 0.044715f * v * v * v));
    return 0.5f * v * (1.0f + t);
}

// ---------------- gating: logitsT[e][n] ----------------
__global__ __launch_bounds__(256) void k_gating(const float* __restrict__ x,
                                                const float* __restrict__ Wdct,
                                                const float* __restrict__ Wgate,
                                                float* __restrict__ logitsT) {
    __shared__ float xs[256][33];   // 256 tokens x 32-d chunk (+1 pad)
    __shared__ float wd[32][64];
    __shared__ float wg[320][8];
    int tid = threadIdx.x;
    int n0 = blockIdx.x * 256;
    for (int i = tid; i < 320 * 8; i += 256) ((float*)wg)[i] = Wgate[i];
    float freq[64];
#pragma unroll
    for (int f = 0; f < 64; ++f) freq[f] = 0.f;
    float lg[8];
#pragma unroll
    for (int e = 0; e < 8; ++e) lg[e] = 0.f;
    for (int c = 0; c < 8; ++c) {
        __syncthreads();
        {
            int col = tid & 31, rbase = tid >> 5;
#pragma unroll
            for (int i = 0; i < 32; ++i) {
                int row = i * 8 + rbase;
                xs[row][col] = x[(size_t)(n0 + row) * DIN + c * 32 + col];
            }
        }
        for (int i = tid; i < 2048; i += 256)
            wd[i >> 6][i & 63] = Wdct[(size_t)(c * 32 + (i >> 6)) * 64 + (i & 63)];
        __syncthreads();
        for (int d = 0; d < 32; ++d) {
            float xv = xs[tid][d];
#pragma unroll
            for (int f = 0; f < 64; ++f) freq[f] += xv * wd[d][f];
#pragma unroll
            for (int e = 0; e < 8; ++e) lg[e] += xv * wg[c * 32 + d][e];
        }
    }
#pragma unroll
    for (int f = 0; f < 64; ++f) {
#pragma unroll
        for (int e = 0; e < 8; ++e) lg[e] += freq[f] * wg[256 + f][e];
    }
    int n = n0 + tid;
#pragma unroll
    for (int e = 0; e < 8; ++e) logitsT[(size_t)e * NTOK + n] = lg[e];
}

// ---------------- per-expert max (as ordered uint) ----------------
__global__ __launch_bounds__(256) void k_colmax(const float* __restrict__ logitsT,
                                                unsigned* __restrict__ meta) {
    __shared__ unsigned sm[256];
    int e = blockIdx.y, tid = threadIdx.x;
    size_t base = (size_t)e * NTOK + (size_t)blockIdx.x * 1024;
    unsigned m = 0;
#pragma unroll
    for (int i = 0; i < 4; ++i) m = max(m, key_of(logitsT[base + i * 256 + tid]));
    sm[tid] = m;
    __syncthreads();
    for (int s = 128; s > 0; s >>= 1) {
        if (tid < s) sm[tid] = max(sm[tid], sm[tid + s]);
        __syncthreads();
    }
    if (tid == 0) atomicMax(&meta[e], sm[0]);
}

// ---------------- per-expert sum of exp (deterministic 2-stage) --------------
__global__ __launch_bounds__(256) void k_colsum_part(const float* __restrict__ logitsT,
                                                     const unsigned* __restrict__ meta,
                                                     float* __restrict__ partials) {
    __shared__ float sm[256];
    int e = blockIdx.y, tid = threadIdx.x;
    float mx = inv_key(meta[e]);
    size_t base = (size_t)e * NTOK + (size_t)blockIdx.x * 512;
    float s = expf(logitsT[base + tid] - mx) + expf(logitsT[base + 256 + tid] - mx);
    sm[tid] = s;
    __syncthreads();
    for (int st = 128; st > 0; st >>= 1) {
        if (tid < st) sm[tid] += sm[tid + st];
        __syncthreads();
    }
    if (tid == 0) partials[e * 128 + blockIdx.x] = sm[0];
}

__global__ __launch_bounds__(128) void k_colsum_final(const float* __restrict__ partials,
                                                      float* __restrict__ colsum) {
    __shared__ float sm[128];
    int e = blockIdx.x, tid = threadIdx.x;
    sm[tid] = partials[e * 128 + tid];
    __syncthreads();
    for (int st = 64; st > 0; st >>= 1) {
        if (tid < st) sm[tid] += sm[tid + st];
        __syncthreads();
    }
    if (tid == 0) colsum[e] = sm[0];
}

// ---------------- radix select: histogram + scan ----------------
__global__ __launch_bounds__(256) void k_hist(const float* __restrict__ logitsT,
                                              unsigned* __restrict__ hist,
                                              const unsigned* __restrict__ meta,
                                              int pass) {
    __shared__ unsigned lh[256];
    int e = blockIdx.y, tid = threadIdx.x;
    lh[tid] = 0;
    __syncthreads();
    unsigned pref = meta[16 + e];
    int shift = 24 - 8 * pass;
    size_t base = (size_t)e * NTOK + (size_t)blockIdx.x * 1024;
#pragma unroll
    for (int i = 0; i < 4; ++i) {
        unsigned k = key_of(logitsT[base + i * 256 + tid]);
        bool ok = (pass == 0) || ((k >> (shift + 8)) == pref);
        if (ok) atomicAdd(&lh[(k >> shift) & 255u], 1u);
    }
    __syncthreads();
    if (lh[tid]) atomicAdd(&hist[((size_t)pass * NEXP + e) * 256 + tid], lh[tid]);
}

__global__ void k_scan(const unsigned* __restrict__ hist,
                       unsigned* __restrict__ meta, int pass) {
    int e = threadIdx.x;
    if (e >= NEXP) return;
    unsigned rem = (pass == 0) ? (unsigned)CAP : meta[24 + e];
    unsigned pref = (pass == 0) ? 0u : meta[16 + e];
    const unsigned* h = &hist[((size_t)pass * NEXP + e) * 256];
    unsigned cum = 0;
    for (int b = 255; b >= 0; --b) {
        unsigned c = h[b];
        if (cum + c >= rem) {
            meta[16 + e] = (pref << 8) | (unsigned)b;
            meta[24 + e] = rem - cum;
            break;
        }
        cum += c;
    }
}

// ---------------- selection / compaction ----------------
__global__ __launch_bounds__(256) void k_select(const float* __restrict__ logitsT,
                                                const unsigned* __restrict__ meta,
                                                unsigned* __restrict__ cnts,
                                                int* __restrict__ idxbuf,
                                                int* __restrict__ ties) {
    int e = blockIdx.y, tid = threadIdx.x;
    unsigned T = meta[16 + e];
    int nbase = blockIdx.x * 1024;
    for (int i = 0; i < 4; ++i) {
        int n = nbase + i * 256 + tid;
        unsigned k = key_of(logitsT[(size_t)e * NTOK + n]);
        if (k > T) {
            unsigned pos = atomicAdd(&cnts[e], 1u);
            idxbuf[e * CAP + pos] = n;
        } else if (k == T) {
            unsigned tp = atomicAdd(&cnts[8 + e], 1u);
            ties[(size_t)e * NTOK + tp] = n;
        }
    }
}

__global__ __launch_bounds__(256) void k_ties(const unsigned* __restrict__ meta,
                                              int* __restrict__ idxbuf,
                                              const int* __restrict__ ties) {
    int e = blockIdx.x, tid = threadIdx.x;
    int m = (int)meta[40 + e];
    int r = (int)meta[24 + e];
    int base = CAP - r;
    const int* tp = &ties[(size_t)e * NTOK];
    if (m == r) {
        for (int i = tid; i < m; i += 256) idxbuf[e * CAP + base + i] = tp[i];
    } else {
        // deterministic: r lowest-indexed ties (lax.top_k tie-break)
        for (int i = tid; i < m; i += 256) {
            int my = tp[i];
            int rank = 0;
            for (int j = 0; j < m; ++j) rank += (tp[j] < my);
            if (rank < r) idxbuf[e * CAP + base + rank] = my;
        }
    }
}

// ---------------- fused expert MLP + scatter ----------------
__global__ __launch_bounds__(256) void k_expert(
    const float* __restrict__ x, const int* __restrict__ band,
    const float* __restrict__ W1, const float* __restrict__ b1,
    const float* __restrict__ A1, const float* __restrict__ B1,
    const float* __restrict__ W2, const float* __restrict__ b2,
    const float* __restrict__ A2, const float* __restrict__ B2,
    const float* __restrict__ logitsT, const unsigned* __restrict__ meta,
    const float* __restrict__ colsum, const int* __restrict__ idxbuf,
    float* __restrict__ y) {
    __shared__ float xe[16][257];
    __shared__ float hbuf[16][512];
    __shared__ float uv[16][8];
    __shared__ int ntok[16];
    __shared__ int btok[16];
    __shared__ float gtok[16];
    int tid = threadIdx.x;
    int bid = blockIdx.x;
    int e = bid / TILES_PER_E;
    int tile = bid % TILES_PER_E;
    if (tid < 16) {
        int n = idxbuf[e * CAP + tile * NTILE + tid];
        ntok[tid] = n;
        btok[tid] = band[n];
        float mx = inv_key(meta[e]);
        gtok[tid] = expf(logitsT[(size_t)e * NTOK + n] - mx) / colsum[e];
    }
    __syncthreads();
#pragma unroll
    for (int t = 0; t < 16; ++t) xe[t][tid] = x[(size_t)ntok[t] * DIN + tid];
    if (tid < 16) xe[tid][256] = (float)btok[tid] * 0.25f;
    __syncthreads();

    // ---- layer 1: each thread 8 tokens x 4 cols ----
    int c4 = tid & 127, tg = tid >> 7;
    float acc[8][4];
    {
        const float4 bb = *(const float4*)&b1[(size_t)e * HID + c4 * 4];
#pragma unroll
        for (int t = 0; t < 8; ++t) {
            acc[t][0] = bb.x; acc[t][1] = bb.y; acc[t][2] = bb.z; acc[t][3] = bb.w;
        }
    }
    {
        const float* Wp = &W1[(size_t)e * 257 * HID + c4 * 4];
        for (int d = 0; d < 257; ++d) {
            float4 w = *(const float4*)&Wp[(size_t)d * HID];
#pragma unroll
            for (int t = 0; t < 8; ++t) {
                float xv = xe[tg * 8 + t][d];
                acc[t][0] += xv * w.x; acc[t][1] += xv * w.y;
                acc[t][2] += xv * w.z; acc[t][3] += xv * w.w;
            }
        }
    }
    // LoRA1 u = 2 * xe @ A1[band]
    if (tid < 128) {
        int t = tid >> 3, r = tid & 7;
        const float* Ap = &A1[(((size_t)e * NBAND + btok[t]) * 257) * RANK + r];
        float s = 0.f;
        for (int d = 0; d < 257; ++d) s += xe[t][d] * Ap[(size_t)d * RANK];
        uv[t][r] = LSCALE * s;
    }
    __syncthreads();
#pragma unroll
    for (int t = 0; t < 8; ++t) {
        int tt = tg * 8 + t;
        const float* Bp = &B1[(((size_t)e * NBAND + btok[tt]) * RANK) * HID + c4 * 4];
        float a0 = acc[t][0], a1 = acc[t][1], a2 = acc[t][2], a3 = acc[t][3];
#pragma unroll
        for (int r = 0; r < 8; ++r) {
            float ur = uv[tt][r];
            float4 bw = *(const float4*)&Bp[(size_t)r * HID];
            a0 += ur * bw.x; a1 += ur * bw.y; a2 += ur * bw.z; a3 += ur * bw.w;
        }
        hbuf[tt][c4 * 4 + 0] = gelu_tanh(a0);
        hbuf[tt][c4 * 4 + 1] = gelu_tanh(a1);
        hbuf[tt][c4 * 4 + 2] = gelu_tanh(a2);
        hbuf[tt][c4 * 4 + 3] = gelu_tanh(a3);
    }
    __syncthreads();

    // ---- layer 2: each thread 4 tokens x 4 cols ----
    int c4b = tid & 63, tg2 = tid >> 6;
    float acc2[4][4];
    {
        const float4 bb = *(const float4*)&b2[(size_t)e * DOUT + c4b * 4];
#pragma unroll
        for (int t = 0; t < 4; ++t) {
            acc2[t][0] = bb.x; acc2[t][1] = bb.y; acc2[t][2] = bb.z; acc2[t][3] = bb.w;
        }
    }
    {
        const float* Wp = &W2[(size_t)e * HID * DOUT + c4b * 4];
        for (int hh = 0; hh < 512; ++hh) {
            float4 w = *(const float4*)&Wp[(size_t)hh * DOUT];
#pragma unroll
            for (int t = 0; t < 4; ++t) {
                float xv = hbuf[tg2 * 4 + t][hh];
                acc2[t][0] += xv * w.x; acc2[t][1] += xv * w.y;
                acc2[t][2] += xv * w.z; acc2[t][3] += xv * w.w;
            }
        }
    }
    // LoRA2 v = 2 * h @ A2[band]   (uv reuse: safe, last read was pre-sync)
    if (tid < 128) {
        int t = tid >> 3, r = tid & 7;
        const float* Ap = &A2[(((size_t)e * NBAND + btok[t]) * HID) * RANK + r];
        float s = 0.f;
        for (int hh = 0; hh < 512; ++hh) s += hbuf[t][hh] * Ap[(size_t)hh * RANK];
        uv[t][r] = LSCALE * s;
    }
    __syncthreads();
#pragma unroll
    for (int t = 0; t < 4; ++t) {
        int tt = tg2 * 4 + t;
        const float* Bp = &B2[(((size_t)e * NBAND + btok[tt]) * RANK) * DOUT + c4b * 4];
        float a0 = acc2[t][0], a1 = acc2[t][1], a2 = acc2[t][2], a3 = acc2[t][3];
#pragma unroll
        for (int r = 0; r < 8; ++r) {
            float ur = uv[tt][r];
            float4 bw = *(const float4*)&Bp[(size_t)r * DOUT];
            a0 += ur * bw.x; a1 += ur * bw.y; a2 += ur * bw.z; a3 += ur * bw.w;
        }
        float g = gtok[tt];
        float* yp = &y[(size_t)ntok[tt] * DOUT + c4b * 4];
        atomicAdd(&yp[0], g * a0);
        atomicAdd(&yp[1], g * a1);
        atomicAdd(&yp[2], g * a2);
        atomicAdd(&yp[3], g * a3);
    }
}

extern "C" void kernel_launch(void* const* d_in, const int* in_sizes, int n_in,
                              void* d_out, int out_size, void* d_ws, size_t ws_size,
                              hipStream_t stream) {
    const float* x = (const float*)d_in[0];
    const int* band = (const int*)d_in[1];
    const float* Wdct = (const float*)d_in[2];
    const float* Wgate = (const float*)d_in[3];
    const float* W1 = (const float*)d_in[4];
    const float* b1 = (const float*)d_in[5];
    const float* A1 = (const float*)d_in[6];
    const float* B1 = (const float*)d_in[7];
    const float* W2 = (const float*)d_in[8];
    const float* b2 = (const float*)d_in[9];
    const float* A2 = (const float*)d_in[10];
    const float* B2 = (const float*)d_in[11];
    float* y = (float*)d_out;

    float* ws = (float*)d_ws;
    float* logitsT = ws;                          // 524288 words
    unsigned* hist = (unsigned*)(ws + 524288);    // 8192 words
    unsigned* meta = (unsigned*)(ws + 532480);    // 64 words
    float* colsum = ws + 532544;                  // 8
    float* partials = ws + 532552;                // 1024
    int* idxbuf = (int*)(ws + 533576);            // 81920
    int* ties = (int*)(ws + 615496);              // 524288

    hipMemsetAsync(d_out, 0, (size_t)NTOK * DOUT * sizeof(float), stream);
    hipMemsetAsync(hist, 0, (8192 + 64) * sizeof(unsigned), stream);

    k_gating<<<NTOK / 256, 256, 0, stream>>>(x, Wdct, Wgate, logitsT);
    k_colmax<<<dim3(64, NEXP), 256, 0, stream>>>(logitsT, meta);
    k_colsum_part<<<dim3(128, NEXP), 256, 0, stream>>>(logitsT, meta, partials);
    k_colsum_final<<<NEXP, 128, 0, stream>>>(partials, colsum);
    for (int p = 0; p < 4; ++p) {
        k_hist<<<dim3(64, NEXP), 256, 0, stream>>>(logitsT, hist, meta, p);
        k_scan<<<1, NEXP, 0, stream>>>(hist, meta, p);
    }
    k_select<<<dim3(64, NEXP), 256, 0, stream>>>(logitsT, meta, &meta[32], idxbuf, ties);
    k_ties<<<NEXP, 256, 0, stream>>>(meta, idxbuf, ties);
    k_expert<<<NEXP * TILES_PER_E, 256, 0, stream>>>(x, band, W1, b1, A1, B1,
                                                     W2, b2, A2, B2, logitsT,
                                                     meta, colsum, idxbuf, y);
}

// Round 3
// 551.300 us; speedup vs baseline: 2.0895x; 2.0895x over previous
//
#include <hip/hip_runtime.h>
#include <hip/hip_bf16.h>
#include <math.h>

#define NTOK 65536
#define DIN 256
#define DOUT 256
#define HID 512
#define NEXP 8
#define NBAND 4
#define RANK 8
#define CAP 10240
#define NTILE 64
#define TILES_PER_E (CAP / NTILE)  // 160

// packed bf16 weight region (ushort elements), offsets in elements
#define W1CAT_PER_E (34 * 9 * 512)            // 156672
#define B1CAT_OFF   (NEXP * W1CAT_PER_E)      // 1253376
#define B1CAT_PER_E (32 * 512)                // 16384
#define W2CAT_OFF   (B1CAT_OFF + NEXP * B1CAT_PER_E)  // 1384448
#define W2CAT_PER_E (18 * 16 * 512)           // 147456
#define B2CAT_OFF   (W2CAT_OFF + NEXP * W2CAT_PER_E)  // 2564096
#define B2CAT_PER_E (16 * 512)                // 8192
#define PK_TOTAL    (B2CAT_OFF + NEXP * B2CAT_PER_E)  // 2629632
#define PK_F32_OFF  1200000                   // f32-word offset of packed region in ws

typedef short s16x8 __attribute__((ext_vector_type(8)));
typedef float f32x4 __attribute__((ext_vector_type(4)));

__device__ __forceinline__ unsigned key_of(float f) {
    unsigned u = __float_as_uint(f);
    return (u & 0x80000000u) ? ~u : (u | 0x80000000u);
}
__device__ __forceinline__ float inv_key(unsigned k) {
    return (k & 0x80000000u) ? __uint_as_float(k & 0x7FFFFFFFu)
                             : __uint_as_float(~k);
}
__device__ __forceinline__ float gelu_tanh(float v) {
    const float c = 0.7978845608028654f;
    float t = tanhf(c * (v + 0.044715f * v * v * v));
    return 0.5f * v * (1.0f + t);
}
__device__ __forceinline__ ushort f2bf(float f) {  // RNE f32->bf16
    unsigned u = __float_as_uint(f);
    return (ushort)((u + 0x7FFFu + ((u >> 16) & 1u)) >> 16);
}

// ---------------- gating: logitsT[e][n] (fp32, unchanged) ----------------
__global__ __launch_bounds__(256) void k_gating(const float* __restrict__ x,
                                                const float* __restrict__ Wdct,
                                                const float* __restrict__ Wgate,
                                                float* __restrict__ logitsT) {
    __shared__ float xs[256][33];
    __shared__ float wd[32][64];
    __shared__ float wg[320][8];
    int tid = threadIdx.x;
    int n0 = blockIdx.x * 256;
    for (int i = tid; i < 320 * 8; i += 256) ((float*)wg)[i] = Wgate[i];
    float freq[64];
#pragma unroll
    for (int f = 0; f < 64; ++f) freq[f] = 0.f;
    float lg[8];
#pragma unroll
    for (int e = 0; e < 8; ++e) lg[e] = 0.f;
    for (int c = 0; c < 8; ++c) {
        __syncthreads();
        {
            int col = tid & 31, rbase = tid >> 5;
#pragma unroll
            for (int i = 0; i < 32; ++i) {
                int row = i * 8 + rbase;
                xs[row][col] = x[(size_t)(n0 + row) * DIN + c * 32 + col];
            }
        }
        for (int i = tid; i < 2048; i += 256)
            wd[i >> 6][i & 63] = Wdct[(size_t)(c * 32 + (i >> 6)) * 64 + (i & 63)];
        __syncthreads();
        for (int d = 0; d < 32; ++d) {
            float xv = xs[tid][d];
#pragma unroll
            for (int f = 0; f < 64; ++f) freq[f] += xv * wd[d][f];
#pragma unroll
            for (int e = 0; e < 8; ++e) lg[e] += xv * wg[c * 32 + d][e];
        }
    }
#pragma unroll
    for (int f = 0; f < 64; ++f) {
#pragma unroll
        for (int e = 0; e < 8; ++e) lg[e] += freq[f] * wg[256 + f][e];
    }
    int n = n0 + tid;
#pragma unroll
    for (int e = 0; e < 8; ++e) logitsT[(size_t)e * NTOK + n] = lg[e];
}

// ---------------- per-expert max ----------------
__global__ __launch_bounds__(256) void k_colmax(const float* __restrict__ logitsT,
                                                unsigned* __restrict__ meta) {
    __shared__ unsigned sm[256];
    int e = blockIdx.y, tid = threadIdx.x;
    size_t base = (size_t)e * NTOK + (size_t)blockIdx.x * 1024;
    unsigned m = 0;
#pragma unroll
    for (int i = 0; i < 4; ++i) m = max(m, key_of(logitsT[base + i * 256 + tid]));
    sm[tid] = m;
    __syncthreads();
    for (int s = 128; s > 0; s >>= 1) {
        if (tid < s) sm[tid] = max(sm[tid], sm[tid + s]);
        __syncthreads();
    }
    if (tid == 0) atomicMax(&meta[e], sm[0]);
}

// ---------------- per-expert sum of exp ----------------
__global__ __launch_bounds__(256) void k_colsum_part(const float* __restrict__ logitsT,
                                                     const unsigned* __restrict__ meta,
                                                     float* __restrict__ partials) {
    __shared__ float sm[256];
    int e = blockIdx.y, tid = threadIdx.x;
    float mx = inv_key(meta[e]);
    size_t base = (size_t)e * NTOK + (size_t)blockIdx.x * 512;
    float s = expf(logitsT[base + tid] - mx) + expf(logitsT[base + 256 + tid] - mx);
    sm[tid] = s;
    __syncthreads();
    for (int st = 128; st > 0; st >>= 1) {
        if (tid < st) sm[tid] += sm[tid + st];
        __syncthreads();
    }
    if (tid == 0) partials[e * 128 + blockIdx.x] = sm[0];
}

__global__ __launch_bounds__(128) void k_colsum_final(const float* __restrict__ partials,
                                                      float* __restrict__ colsum) {
    __shared__ float sm[128];
    int e = blockIdx.x, tid = threadIdx.x;
    sm[tid] = partials[e * 128 + tid];
    __syncthreads();
    for (int st = 64; st > 0; st >>= 1) {
        if (tid < st) sm[tid] += sm[tid + st];
        __syncthreads();
    }
    if (tid == 0) colsum[e] = sm[0];
}

// ---------------- radix select ----------------
__global__ __launch_bounds__(256) void k_hist(const float* __restrict__ logitsT,
                                              unsigned* __restrict__ hist,
                                              const unsigned* __restrict__ meta,
                                              int pass) {
    __shared__ unsigned lh[256];
    int e = blockIdx.y, tid = threadIdx.x;
    lh[tid] = 0;
    __syncthreads();
    unsigned pref = meta[16 + e];
    int shift = 24 - 8 * pass;
    size_t base = (size_t)e * NTOK + (size_t)blockIdx.x * 1024;
#pragma unroll
    for (int i = 0; i < 4; ++i) {
        unsigned k = key_of(logitsT[base + i * 256 + tid]);
        bool ok = (pass == 0) || ((k >> (shift + 8)) == pref);
        if (ok) atomicAdd(&lh[(k >> shift) & 255u], 1u);
    }
    __syncthreads();
    if (lh[tid]) atomicAdd(&hist[((size_t)pass * NEXP + e) * 256 + tid], lh[tid]);
}

__global__ void k_scan(const unsigned* __restrict__ hist,
                       unsigned* __restrict__ meta, int pass) {
    int e = threadIdx.x;
    if (e >= NEXP) return;
    unsigned rem = (pass == 0) ? (unsigned)CAP : meta[24 + e];
    unsigned pref = (pass == 0) ? 0u : meta[16 + e];
    const unsigned* h = &hist[((size_t)pass * NEXP + e) * 256];
    unsigned cum = 0;
    for (int b = 255; b >= 0; --b) {
        unsigned c = h[b];
        if (cum + c >= rem) {
            meta[16 + e] = (pref << 8) | (unsigned)b;
            meta[24 + e] = rem - cum;
            break;
        }
        cum += c;
    }
}

__global__ __launch_bounds__(256) void k_select(const float* __restrict__ logitsT,
                                                const unsigned* __restrict__ meta,
                                                unsigned* __restrict__ cnts,
                                                int* __restrict__ idxbuf,
                                                int* __restrict__ ties) {
    int e = blockIdx.y, tid = threadIdx.x;
    unsigned T = meta[16 + e];
    int nbase = blockIdx.x * 1024;
    for (int i = 0; i < 4; ++i) {
        int n = nbase + i * 256 + tid;
        unsigned k = key_of(logitsT[(size_t)e * NTOK + n]);
        if (k > T) {
            unsigned pos = atomicAdd(&cnts[e], 1u);
            idxbuf[e * CAP + pos] = n;
        } else if (k == T) {
            unsigned tp = atomicAdd(&cnts[8 + e], 1u);
            ties[(size_t)e * NTOK + tp] = n;
        }
    }
}

__global__ __launch_bounds__(256) void k_ties(const unsigned* __restrict__ meta,
                                              int* __restrict__ idxbuf,
                                              const int* __restrict__ ties) {
    int e = blockIdx.x, tid = threadIdx.x;
    int m = (int)meta[40 + e];
    int r = (int)meta[24 + e];
    int base = CAP - r;
    const int* tp = &ties[(size_t)e * NTOK];
    if (m == r) {
        for (int i = tid; i < m; i += 256) idxbuf[e * CAP + base + i] = tp[i];
    } else {
        for (int i = tid; i < m; i += 256) {
            int my = tp[i];
            int rank = 0;
            for (int j = 0; j < m; ++j) rank += (tp[j] < my);
            if (rank < r) idxbuf[e * CAP + base + rank] = my;
        }
    }
}

// ---------------- weight packing into MFMA fragment order (bf16) ------------
// 16x16x32 fragment: elem (lane,j): k = s*32 + (lane>>4)*8 + j, col = t*16 + (lane&15)
__global__ __launch_bounds__(256) void k_prep(const float* __restrict__ W1,
                                              const float* __restrict__ A1,
                                              const float* __restrict__ B1,
                                              const float* __restrict__ W2,
                                              const float* __restrict__ A2,
                                              const float* __restrict__ B2,
                                              ushort* __restrict__ pk) {
    int id = blockIdx.x * 256 + threadIdx.x;
    if (id >= PK_TOTAL) return;
    float val;
    if (id < B1CAT_OFF) {
        int e = id / W1CAT_PER_E, rem = id % W1CAT_PER_E;
        int t = rem / (9 * 512); rem %= 9 * 512;
        int s = rem / 512; int q = rem & 511;
        int l = q >> 3, j = q & 7;
        int k = s * 32 + ((l >> 4) << 3) + j;
        int col = t * 16 + (l & 15);
        if (k > 256) val = 0.f;
        else if (col < 512) val = W1[((size_t)e * 257 + k) * 512 + col];
        else {
            int cu = col - 512;
            val = A1[(((size_t)e * NBAND + (cu >> 3)) * 257 + k) * RANK + (cu & 7)];
        }
    } else if (id < W2CAT_OFF) {
        int id2 = id - B1CAT_OFF;
        int e = id2 / B1CAT_PER_E, rem = id2 % B1CAT_PER_E;
        int t = rem / 512; int q = rem & 511;
        int l = q >> 3, j = q & 7;
        int k32 = ((l >> 4) << 3) + j;
        int col = t * 16 + (l & 15);
        val = 2.0f * B1[(((size_t)e * NBAND + (k32 >> 3)) * RANK + (k32 & 7)) * 512 + col];
    } else if (id < B2CAT_OFF) {
        int id2 = id - W2CAT_OFF;
        int e = id2 / W2CAT_PER_E, rem = id2 % W2CAT_PER_E;
        int t = rem / (16 * 512); rem %= 16 * 512;
        int s = rem / 512; int q = rem & 511;
        int l = q >> 3, j = q & 7;
        int k = s * 32 + ((l >> 4) << 3) + j;
        int col = t * 16 + (l & 15);
        if (col < 256) val = W2[((size_t)e * 512 + k) * 256 + col];
        else {
            int cv = col - 256;
            val = A2[(((size_t)e * NBAND + (cv >> 3)) * 512 + k) * RANK + (cv & 7)];
        }
    } else {
        int id2 = id - B2CAT_OFF;
        int e = id2 / B2CAT_PER_E, rem = id2 % B2CAT_PER_E;
        int t = rem / 512; int q = rem & 511;
        int l = q >> 3, j = q & 7;
        int k32 = ((l >> 4) << 3) + j;
        int col = t * 16 + (l & 15);
        val = 2.0f * B2[(((size_t)e * NBAND + (k32 >> 3)) * RANK + (k32 & 7)) * 256 + col];
    }
    pk[id] = f2bf(val);
}

// ---------------- fused expert MLP (MFMA) + scatter ----------------
// 4 waves/block, each wave privately handles 16 tokens.
__global__ __launch_bounds__(256) void k_expert(
    const float* __restrict__ x, const int* __restrict__ band,
    const float* __restrict__ b1, const float* __restrict__ b2,
    const ushort* __restrict__ pk,
    const float* __restrict__ logitsT, const unsigned* __restrict__ meta,
    const float* __restrict__ colsum, const int* __restrict__ idxbuf,
    float* __restrict__ y) {
    __shared__ ushort sc[4][16 * 40];   // per-wave D->A shuffle scratch (16 rows x 32 cols, stride 40)
    __shared__ int s_tok[4][16];
    __shared__ int s_band[4][16];
    __shared__ float s_g[4][16];

    int tid = threadIdx.x, w = tid >> 6, lane = tid & 63;
    int bid = blockIdx.x;
    int e = bid / TILES_PER_E;
    int tile = bid % TILES_PER_E;

    if (lane < 16) {
        int n = idxbuf[e * CAP + tile * NTILE + w * 16 + lane];
        s_tok[w][lane] = n;
        s_band[w][lane] = band[n];
        float mx = inv_key(meta[e]);
        s_g[w][lane] = expf(logitsT[(size_t)e * NTOK + n] - mx) / colsum[e];
    }
    __syncthreads();

    int l15 = lane & 15, lg = lane >> 4;
    ushort* scw = &sc[4 - 4][0];  // silence unused warn pattern
    scw = &sc[w][0];

    // ---- load A-frags for layer 1 (K=288: 9 ksteps) ----
    s16x8 a1[9];
    {
        int mytok = s_tok[w][l15];
        const float* xrow = x + (size_t)mytok * DIN;
        int kg = lg << 3;
#pragma unroll
        for (int s = 0; s < 8; ++s) {
            float4 p = *(const float4*)&xrow[s * 32 + kg];
            float4 q = *(const float4*)&xrow[s * 32 + kg + 4];
            s16x8 a;
            a[0] = (short)f2bf(p.x); a[1] = (short)f2bf(p.y);
            a[2] = (short)f2bf(p.z); a[3] = (short)f2bf(p.w);
            a[4] = (short)f2bf(q.x); a[5] = (short)f2bf(q.y);
            a[6] = (short)f2bf(q.z); a[7] = (short)f2bf(q.w);
            a1[s] = a;
        }
        s16x8 a = (s16x8)(short)0;
        if (lane < 16) a[0] = (short)f2bf((float)s_band[w][l15] * 0.25f);
        a1[8] = a;
    }

    const ushort* w1base = pk + (size_t)e * W1CAT_PER_E;
    const ushort* b1base = pk + B1CAT_OFF + (size_t)e * B1CAT_PER_E;
    const ushort* w2base = pk + W2CAT_OFF + (size_t)e * W2CAT_PER_E;
    const ushort* b2base = pk + B2CAT_OFF + (size_t)e * B2CAT_PER_E;

    // ---- LoRA1 u = xe @ A1cat (tiles 32,33), band-mask -> ufrag ----
    s16x8 ufrag;
    {
#pragma unroll
        for (int t = 32; t <= 33; ++t) {
            f32x4 acc = {0.f, 0.f, 0.f, 0.f};
#pragma unroll
            for (int s = 0; s < 9; ++s) {
                s16x8 b = *(const s16x8*)(w1base + ((size_t)t * 9 + s) * 512 + lane * 8);
                acc = __builtin_amdgcn_mfma_f32_16x16x32_bf16(a1[s], b, acc, 0, 0, 0);
            }
            int colbase = (t - 32) * 16 + l15;
#pragma unroll
            for (int r = 0; r < 4; ++r) {
                int row = lg * 4 + r;
                float v = ((colbase >> 3) == s_band[w][row]) ? acc[r] : 0.f;
                scw[row * 40 + colbase] = f2bf(v);
            }
        }
        asm volatile("s_waitcnt lgkmcnt(0)" ::: "memory");
        ufrag = *(const s16x8*)&scw[l15 * 40 + lg * 8];
    }

    // ---- layer 1 main: h tiles -> a2 A-frags (K=512: 16 ksteps) ----
    s16x8 a2[16];
    for (int s2 = 0; s2 < 16; ++s2) {
#pragma unroll
        for (int half = 0; half < 2; ++half) {
            int t = s2 * 2 + half;
            float bv = b1[(size_t)e * HID + t * 16 + l15];
            f32x4 acc = {bv, bv, bv, bv};
#pragma unroll
            for (int s = 0; s < 9; ++s) {
                s16x8 b = *(const s16x8*)(w1base + ((size_t)t * 9 + s) * 512 + lane * 8);
                acc = __builtin_amdgcn_mfma_f32_16x16x32_bf16(a1[s], b, acc, 0, 0, 0);
            }
            {
                s16x8 b = *(const s16x8*)(b1base + (size_t)t * 512 + lane * 8);
                acc = __builtin_amdgcn_mfma_f32_16x16x32_bf16(ufrag, b, acc, 0, 0, 0);
            }
            int colbase = half * 16 + l15;
#pragma unroll
            for (int r = 0; r < 4; ++r) {
                int row = lg * 4 + r;
                scw[row * 40 + colbase] = f2bf(gelu_tanh(acc[r]));
            }
        }
        asm volatile("s_waitcnt lgkmcnt(0)" ::: "memory");
        a2[s2] = *(const s16x8*)&scw[l15 * 40 + lg * 8];
    }

    // ---- LoRA2 v = h @ A2cat (tiles 16,17), band-mask -> vfrag ----
    s16x8 vfrag;
    {
#pragma unroll
        for (int t2 = 16; t2 <= 17; ++t2) {
            f32x4 acc = {0.f, 0.f, 0.f, 0.f};
#pragma unroll
            for (int s = 0; s < 16; ++s) {
                s16x8 b = *(const s16x8*)(w2base + ((size_t)t2 * 16 + s) * 512 + lane * 8);
                acc = __builtin_amdgcn_mfma_f32_16x16x32_bf16(a2[s], b, acc, 0, 0, 0);
            }
            int colbase = (t2 - 16) * 16 + l15;
#pragma unroll
            for (int r = 0; r < 4; ++r) {
                int row = lg * 4 + r;
                float v = ((colbase >> 3) == s_band[w][row]) ? acc[r] : 0.f;
                scw[row * 40 + colbase] = f2bf(v);
            }
        }
        asm volatile("s_waitcnt lgkmcnt(0)" ::: "memory");
        vfrag = *(const s16x8*)&scw[l15 * 40 + lg * 8];
    }

    // ---- layer 2 main + scatter ----
    float g4[4];
    int tok4[4];
#pragma unroll
    for (int r = 0; r < 4; ++r) {
        int row = lg * 4 + r;
        g4[r] = s_g[w][row];
        tok4[r] = s_tok[w][row];
    }
    for (int t2 = 0; t2 < 16; ++t2) {
        float bv = b2[(size_t)e * DOUT + t2 * 16 + l15];
        f32x4 acc = {bv, bv, bv, bv};
#pragma unroll
        for (int s = 0; s < 16; ++s) {
            s16x8 b = *(const s16x8*)(w2base + ((size_t)t2 * 16 + s) * 512 + lane * 8);
            acc = __builtin_amdgcn_mfma_f32_16x16x32_bf16(a2[s], b, acc, 0, 0, 0);
        }
        {
            s16x8 b = *(const s16x8*)(b2base + (size_t)t2 * 512 + lane * 8);
            acc = __builtin_amdgcn_mfma_f32_16x16x32_bf16(vfrag, b, acc, 0, 0, 0);
        }
        int col = t2 * 16 + l15;
#pragma unroll
        for (int r = 0; r < 4; ++r) {
            atomicAdd(&y[(size_t)tok4[r] * DOUT + col], g4[r] * acc[r]);
        }
    }
}

extern "C" void kernel_launch(void* const* d_in, const int* in_sizes, int n_in,
                              void* d_out, int out_size, void* d_ws, size_t ws_size,
                              hipStream_t stream) {
    const float* x = (const float*)d_in[0];
    const int* band = (const int*)d_in[1];
    const float* Wdct = (const float*)d_in[2];
    const float* Wgate = (const float*)d_in[3];
    const float* W1 = (const float*)d_in[4];
    const float* b1 = (const float*)d_in[5];
    const float* A1 = (const float*)d_in[6];
    const float* B1 = (const float*)d_in[7];
    const float* W2 = (const float*)d_in[8];
    const float* b2 = (const float*)d_in[9];
    const float* A2 = (const float*)d_in[10];
    const float* B2 = (const float*)d_in[11];
    float* y = (float*)d_out;

    float* ws = (float*)d_ws;
    float* logitsT = ws;                          // 524288 words
    unsigned* hist = (unsigned*)(ws + 524288);    // 8192 words
    unsigned* meta = (unsigned*)(ws + 532480);    // 64 words
    float* colsum = ws + 532544;                  // 8
    float* partials = ws + 532552;                // 1024
    int* idxbuf = (int*)(ws + 533576);            // 81920
    int* ties = (int*)(ws + 615496);              // 524288 (ends 1139784)
    ushort* pk = (ushort*)(ws + PK_F32_OFF);      // 2629632 bf16 = 5.26 MB

    hipMemsetAsync(d_out, 0, (size_t)NTOK * DOUT * sizeof(float), stream);
    hipMemsetAsync(hist, 0, (8192 + 64) * sizeof(unsigned), stream);

    k_prep<<<(PK_TOTAL + 255) / 256, 256, 0, stream>>>(W1, A1, B1, W2, A2, B2, pk);
    k_gating<<<NTOK / 256, 256, 0, stream>>>(x, Wdct, Wgate, logitsT);
    k_colmax<<<dim3(64, NEXP), 256, 0, stream>>>(logitsT, meta);
    k_colsum_part<<<dim3(128, NEXP), 256, 0, stream>>>(logitsT, meta, partials);
    k_colsum_final<<<NEXP, 128, 0, stream>>>(partials, colsum);
    for (int p = 0; p < 4; ++p) {
        k_hist<<<dim3(64, NEXP), 256, 0, stream>>>(logitsT, hist, meta, p);
        k_scan<<<1, NEXP, 0, stream>>>(hist, meta, p);
    }
    k_select<<<dim3(64, NEXP), 256, 0, stream>>>(logitsT, meta, &meta[32], idxbuf, ties);
    k_ties<<<NEXP, 256, 0, stream>>>(meta, idxbuf, ties);
    k_expert<<<NEXP * TILES_PER_E, 256, 0, stream>>>(x, band, b1, b2, pk,
                                                     logitsT, meta, colsum, idxbuf, y);
}

// Round 4
// 483.974 us; speedup vs baseline: 2.3801x; 1.1391x over previous
//
#include <hip/hip_runtime.h>
#include <hip/hip_bf16.h>
#include <math.h>

#define NTOK 65536
#define DIN 256
#define DOUT 256
#define HID 512
#define NEXP 8
#define NBAND 4
#define RANK 8
#define CAP 10240
#define NTILE 32
#define TILES_PER_E (CAP / NTILE)  // 320

// packed bf16 weight region (ushort elements), offsets in elements
#define W1CAT_PER_E (34 * 9 * 512)            // 156672
#define B1CAT_OFF   (NEXP * W1CAT_PER_E)      // 1253376
#define B1CAT_PER_E (32 * 512)                // 16384
#define W2CAT_OFF   (B1CAT_OFF + NEXP * B1CAT_PER_E)  // 1384448
#define W2CAT_PER_E (18 * 16 * 512)           // 147456
#define B2CAT_OFF   (W2CAT_OFF + NEXP * W2CAT_PER_E)  // 2564096
#define B2CAT_PER_E (16 * 512)                // 8192
#define PK_TOTAL    (B2CAT_OFF + NEXP * B2CAT_PER_E)  // 2629632
#define PK_F32_OFF  1200000                   // f32-word offset of packed region in ws

typedef short s16x8 __attribute__((ext_vector_type(8)));
typedef float f32x4 __attribute__((ext_vector_type(4)));

__device__ __forceinline__ unsigned key_of(float f) {
    unsigned u = __float_as_uint(f);
    return (u & 0x80000000u) ? ~u : (u | 0x80000000u);
}
__device__ __forceinline__ float inv_key(unsigned k) {
    return (k & 0x80000000u) ? __uint_as_float(k & 0x7FFFFFFFu)
                             : __uint_as_float(~k);
}
__device__ __forceinline__ float gelu_tanh(float v) {
    const float c = 0.7978845608028654f;
    float t = tanhf(c * (v + 0.044715f * v * v * v));
    return 0.5f * v * (1.0f + t);
}
__device__ __forceinline__ ushort f2bf(float f) {  // RNE f32->bf16
    unsigned u = __float_as_uint(f);
    return (ushort)((u + 0x7FFFu + ((u >> 16) & 1u)) >> 16);
}

// ---------------- gating: logitsT[e][n] + fused per-expert max --------------
__global__ __launch_bounds__(256) void k_gating(const float* __restrict__ x,
                                                const float* __restrict__ Wdct,
                                                const float* __restrict__ Wgate,
                                                float* __restrict__ logitsT,
                                                unsigned* __restrict__ meta) {
    __shared__ float xs[256][33];
    __shared__ float wd[32][64];
    __shared__ float wg[320][8];
    __shared__ unsigned red4[4];
    int tid = threadIdx.x;
    int n0 = blockIdx.x * 256;
    for (int i = tid; i < 320 * 8; i += 256) ((float*)wg)[i] = Wgate[i];
    float freq[64];
#pragma unroll
    for (int f = 0; f < 64; ++f) freq[f] = 0.f;
    float lg[8];
#pragma unroll
    for (int e = 0; e < 8; ++e) lg[e] = 0.f;
    for (int c = 0; c < 8; ++c) {
        __syncthreads();
        {
            int col = tid & 31, rbase = tid >> 5;
#pragma unroll
            for (int i = 0; i < 32; ++i) {
                int row = i * 8 + rbase;
                xs[row][col] = x[(size_t)(n0 + row) * DIN + c * 32 + col];
            }
        }
        for (int i = tid; i < 2048; i += 256)
            wd[i >> 6][i & 63] = Wdct[(size_t)(c * 32 + (i >> 6)) * 64 + (i & 63)];
        __syncthreads();
        for (int d = 0; d < 32; ++d) {
            float xv = xs[tid][d];
#pragma unroll
            for (int f = 0; f < 64; ++f) freq[f] += xv * wd[d][f];
#pragma unroll
            for (int e = 0; e < 8; ++e) lg[e] += xv * wg[c * 32 + d][e];
        }
    }
#pragma unroll
    for (int f = 0; f < 64; ++f) {
#pragma unroll
        for (int e = 0; e < 8; ++e) lg[e] += freq[f] * wg[256 + f][e];
    }
    int n = n0 + tid;
#pragma unroll
    for (int e = 0; e < 8; ++e) logitsT[(size_t)e * NTOK + n] = lg[e];
    // fused column-max (per expert) via wave shuffle + block reduce
    for (int e = 0; e < 8; ++e) {
        unsigned k = key_of(lg[e]);
#pragma unroll
        for (int off = 32; off > 0; off >>= 1) {
            unsigned o = __shfl_xor(k, off);
            k = max(k, o);
        }
        if ((tid & 63) == 0) red4[tid >> 6] = k;
        __syncthreads();
        if (tid == 0) {
            unsigned m = max(max(red4[0], red4[1]), max(red4[2], red4[3]));
            atomicMax(&meta[e], m);
        }
        __syncthreads();
    }
}

// ---------------- per-expert sum of exp ----------------
__global__ __launch_bounds__(256) void k_colsum_part(const float* __restrict__ logitsT,
                                                     const unsigned* __restrict__ meta,
                                                     float* __restrict__ partials) {
    __shared__ float sm[256];
    int e = blockIdx.y, tid = threadIdx.x;
    float mx = inv_key(meta[e]);
    size_t base = (size_t)e * NTOK + (size_t)blockIdx.x * 512;
    float s = expf(logitsT[base + tid] - mx) + expf(logitsT[base + 256 + tid] - mx);
    sm[tid] = s;
    __syncthreads();
    for (int st = 128; st > 0; st >>= 1) {
        if (tid < st) sm[tid] += sm[tid + st];
        __syncthreads();
    }
    if (tid == 0) partials[e * 128 + blockIdx.x] = sm[0];
}

__global__ __launch_bounds__(128) void k_colsum_final(const float* __restrict__ partials,
                                                      float* __restrict__ colsum) {
    __shared__ float sm[128];
    int e = blockIdx.x, tid = threadIdx.x;
    sm[tid] = partials[e * 128 + tid];
    __syncthreads();
    for (int st = 64; st > 0; st >>= 1) {
        if (tid < st) sm[tid] += sm[tid + st];
        __syncthreads();
    }
    if (tid == 0) colsum[e] = sm[0];
}

// ---------------- radix select ----------------
__global__ __launch_bounds__(256) void k_hist(const float* __restrict__ logitsT,
                                              unsigned* __restrict__ hist,
                                              const unsigned* __restrict__ meta,
                                              int pass) {
    __shared__ unsigned lh[256];
    int e = blockIdx.y, tid = threadIdx.x;
    lh[tid] = 0;
    __syncthreads();
    unsigned pref = meta[16 + e];
    int shift = 24 - 8 * pass;
    size_t base = (size_t)e * NTOK + (size_t)blockIdx.x * 1024;
#pragma unroll
    for (int i = 0; i < 4; ++i) {
        unsigned k = key_of(logitsT[base + i * 256 + tid]);
        bool ok = (pass == 0) || ((k >> (shift + 8)) == pref);
        if (ok) atomicAdd(&lh[(k >> shift) & 255u], 1u);
    }
    __syncthreads();
    if (lh[tid]) atomicAdd(&hist[((size_t)pass * NEXP + e) * 256 + tid], lh[tid]);
}

// parallel scan: one block per expert, suffix-sum over 256 bins
__global__ __launch_bounds__(256) void k_scan2(const unsigned* __restrict__ hist,
                                               unsigned* __restrict__ meta, int pass) {
    __shared__ unsigned s[256];
    int e = blockIdx.x, tid = threadIdx.x;
    unsigned rem = (pass == 0) ? (unsigned)CAP : meta[24 + e];
    unsigned pref = (pass == 0) ? 0u : meta[16 + e];
    unsigned c = hist[((size_t)pass * NEXP + e) * 256 + tid];
    s[tid] = c;
    __syncthreads();
    for (int off = 1; off < 256; off <<= 1) {
        unsigned add = (tid + off < 256) ? s[tid + off] : 0u;
        __syncthreads();
        s[tid] += add;
        __syncthreads();
    }
    // s[b] = sum_{b'>=b} c[b'] (non-increasing in b). pick largest b with s[b] >= rem
    if (s[tid] >= rem && (tid == 255 || s[tid + 1] < rem)) {
        meta[16 + e] = (pref << 8) | (unsigned)tid;
        meta[24 + e] = rem - (s[tid] - c);
    }
}

__global__ __launch_bounds__(256) void k_select(const float* __restrict__ logitsT,
                                                const unsigned* __restrict__ meta,
                                                unsigned* __restrict__ cnts,
                                                int* __restrict__ idxbuf,
                                                int* __restrict__ ties) {
    int e = blockIdx.y, tid = threadIdx.x;
    unsigned T = meta[16 + e];
    int nbase = blockIdx.x * 1024;
    for (int i = 0; i < 4; ++i) {
        int n = nbase + i * 256 + tid;
        unsigned k = key_of(logitsT[(size_t)e * NTOK + n]);
        if (k > T) {
            unsigned pos = atomicAdd(&cnts[e], 1u);
            idxbuf[e * CAP + pos] = n;
        } else if (k == T) {
            unsigned tp = atomicAdd(&cnts[8 + e], 1u);
            ties[(size_t)e * NTOK + tp] = n;
        }
    }
}

__global__ __launch_bounds__(256) void k_ties(const unsigned* __restrict__ meta,
                                              int* __restrict__ idxbuf,
                                              const int* __restrict__ ties) {
    int e = blockIdx.x, tid = threadIdx.x;
    int m = (int)meta[40 + e];
    int r = (int)meta[24 + e];
    int base = CAP - r;
    const int* tp = &ties[(size_t)e * NTOK];
    if (m == r) {
        for (int i = tid; i < m; i += 256) idxbuf[e * CAP + base + i] = tp[i];
    } else {
        for (int i = tid; i < m; i += 256) {
            int my = tp[i];
            int rank = 0;
            for (int j = 0; j < m; ++j) rank += (tp[j] < my);
            if (rank < r) idxbuf[e * CAP + base + rank] = my;
        }
    }
}

// ---------------- weight packing into MFMA fragment order (bf16) ------------
__global__ __launch_bounds__(256) void k_prep(const float* __restrict__ W1,
                                              const float* __restrict__ A1,
                                              const float* __restrict__ B1,
                                              const float* __restrict__ W2,
                                              const float* __restrict__ A2,
                                              const float* __restrict__ B2,
                                              ushort* __restrict__ pk) {
    int id = blockIdx.x * 256 + threadIdx.x;
    if (id >= PK_TOTAL) return;
    float val;
    if (id < B1CAT_OFF) {
        int e = id / W1CAT_PER_E, rem = id % W1CAT_PER_E;
        int t = rem / (9 * 512); rem %= 9 * 512;
        int s = rem / 512; int q = rem & 511;
        int l = q >> 3, j = q & 7;
        int k = s * 32 + ((l >> 4) << 3) + j;
        int col = t * 16 + (l & 15);
        if (k > 256) val = 0.f;
        else if (col < 512) val = W1[((size_t)e * 257 + k) * 512 + col];
        else {
            int cu = col - 512;
            val = A1[(((size_t)e * NBAND + (cu >> 3)) * 257 + k) * RANK + (cu & 7)];
        }
    } else if (id < W2CAT_OFF) {
        int id2 = id - B1CAT_OFF;
        int e = id2 / B1CAT_PER_E, rem = id2 % B1CAT_PER_E;
        int t = rem / 512; int q = rem & 511;
        int l = q >> 3, j = q & 7;
        int k32 = ((l >> 4) << 3) + j;
        int col = t * 16 + (l & 15);
        val = 2.0f * B1[(((size_t)e * NBAND + (k32 >> 3)) * RANK + (k32 & 7)) * 512 + col];
    } else if (id < B2CAT_OFF) {
        int id2 = id - W2CAT_OFF;
        int e = id2 / W2CAT_PER_E, rem = id2 % W2CAT_PER_E;
        int t = rem / (16 * 512); rem %= 16 * 512;
        int s = rem / 512; int q = rem & 511;
        int l = q >> 3, j = q & 7;
        int k = s * 32 + ((l >> 4) << 3) + j;
        int col = t * 16 + (l & 15);
        if (col < 256) val = W2[((size_t)e * 512 + k) * 256 + col];
        else {
            int cv = col - 256;
            val = A2[(((size_t)e * NBAND + (cv >> 3)) * 512 + k) * RANK + (cv & 7)];
        }
    } else {
        int id2 = id - B2CAT_OFF;
        int e = id2 / B2CAT_PER_E, rem = id2 % B2CAT_PER_E;
        int t = rem / 512; int q = rem & 511;
        int l = q >> 3, j = q & 7;
        int k32 = ((l >> 4) << 3) + j;
        int col = t * 16 + (l & 15);
        val = 2.0f * B2[(((size_t)e * NBAND + (k32 >> 3)) * RANK + (k32 & 7)) * 256 + col];
    }
    pk[id] = f2bf(val);
}

// ---------------- fused expert MLP (MFMA) + scatter ----------------
// 2 waves/block, wave-private 16 tokens; h in swizzled wave-private LDS.
// e = bid&7 pins each expert to one XCD's L2; tile loops rotated per wave.
__global__ __launch_bounds__(128) void k_expert(
    const float* __restrict__ x, const int* __restrict__ band,
    const float* __restrict__ b1, const float* __restrict__ b2,
    const ushort* __restrict__ pk,
    const float* __restrict__ logitsT, const unsigned* __restrict__ meta,
    const float* __restrict__ colsum, const int* __restrict__ idxbuf,
    float* __restrict__ y) {
    __shared__ ushort h_lds[2][8192];   // per-wave 16x512 bf16, XOR-swizzled
    __shared__ ushort sc[2][16 * 40];   // shuffle scratch (stride 40 breaks conflicts)
    __shared__ int s_tok[2][16];
    __shared__ int s_band[2][16];
    __shared__ float s_g[2][16];

    int tid = threadIdx.x, w = tid >> 6, lane = tid & 63;
    int bid = blockIdx.x;
    int e = bid & 7;            // XCD-pinned expert
    int tile = bid >> 3;        // 0..319

    if (lane < 16) {
        int n = idxbuf[e * CAP + tile * NTILE + w * 16 + lane];
        s_tok[w][lane] = n;
        s_band[w][lane] = band[n];
        float mx = inv_key(meta[e]);
        s_g[w][lane] = expf(logitsT[(size_t)e * NTOK + n] - mx) / colsum[e];
    }
    __syncthreads();

    int l15 = lane & 15, lg = lane >> 4;
    ushort* scw = &sc[w][0];
    ushort* hw = &h_lds[w][0];
    int rotw = tile * 2 + w;    // de-lockstep seed

    // ---- A-frags for layer 1 (K=288: 9 ksteps), registers (static index) ----
    s16x8 a1[9];
    {
        int mytok = s_tok[w][l15];
        const float* xrow = x + (size_t)mytok * DIN;
        int kg = lg << 3;
#pragma unroll
        for (int s = 0; s < 8; ++s) {
            float4 p = *(const float4*)&xrow[s * 32 + kg];
            float4 q = *(const float4*)&xrow[s * 32 + kg + 4];
            s16x8 a;
            a[0] = (short)f2bf(p.x); a[1] = (short)f2bf(p.y);
            a[2] = (short)f2bf(p.z); a[3] = (short)f2bf(p.w);
            a[4] = (short)f2bf(q.x); a[5] = (short)f2bf(q.y);
            a[6] = (short)f2bf(q.z); a[7] = (short)f2bf(q.w);
            a1[s] = a;
        }
        s16x8 a = (s16x8)(short)0;
        if (lane < 16) a[0] = (short)f2bf((float)s_band[w][l15] * 0.25f);
        a1[8] = a;
    }

    const ushort* w1base = pk + (size_t)e * W1CAT_PER_E;
    const ushort* b1base = pk + B1CAT_OFF + (size_t)e * B1CAT_PER_E;
    const ushort* w2base = pk + W2CAT_OFF + (size_t)e * W2CAT_PER_E;
    const ushort* b2base = pk + B2CAT_OFF + (size_t)e * B2CAT_PER_E;

    // ---- LoRA1 u = xe @ A1cat (tiles 32,33), band-mask -> ufrag ----
    s16x8 ufrag;
    {
        for (int i = 0; i < 2; ++i) {
            int t = 32 + ((i + w) & 1);
            f32x4 acc = {0.f, 0.f, 0.f, 0.f};
#pragma unroll
            for (int s = 0; s < 9; ++s) {
                s16x8 b = *(const s16x8*)(w1base + ((size_t)t * 9 + s) * 512 + lane * 8);
                acc = __builtin_amdgcn_mfma_f32_16x16x32_bf16(a1[s], b, acc, 0, 0, 0);
            }
            int colbase = (t - 32) * 16 + l15;
#pragma unroll
            for (int r = 0; r < 4; ++r) {
                int row = lg * 4 + r;
                float v = ((colbase >> 3) == s_band[w][row]) ? acc[r] : 0.f;
                scw[row * 40 + colbase] = f2bf(v);
            }
        }
        asm volatile("s_waitcnt lgkmcnt(0)" ::: "memory");
        __builtin_amdgcn_sched_barrier(0);
        ufrag = *(const s16x8*)&scw[l15 * 40 + lg * 8];
    }

    // ---- layer 1: rotated tiles, gelu(h) -> swizzled wave-private LDS ----
    for (int i = 0; i < 32; ++i) {
        int t = (i + rotw) & 31;
        float bv = b1[(size_t)e * HID + t * 16 + l15];
        f32x4 acc = {bv, bv, bv, bv};
#pragma unroll
        for (int s = 0; s < 9; ++s) {
            s16x8 b = *(const s16x8*)(w1base + ((size_t)t * 9 + s) * 512 + lane * 8);
            acc = __builtin_amdgcn_mfma_f32_16x16x32_bf16(a1[s], b, acc, 0, 0, 0);
        }
        {
            s16x8 b = *(const s16x8*)(b1base + (size_t)t * 512 + lane * 8);
            acc = __builtin_amdgcn_mfma_f32_16x16x32_bf16(ufrag, b, acc, 0, 0, 0);
        }
#pragma unroll
        for (int r = 0; r < 4; ++r) {
            int row = lg * 4 + r;
            int boff = (row * 1024 + (t * 16 + l15) * 2) ^ ((row & 7) << 4);
            hw[boff >> 1] = f2bf(gelu_tanh(acc[r]));
        }
    }
    asm volatile("s_waitcnt lgkmcnt(0)" ::: "memory");
    __builtin_amdgcn_sched_barrier(0);

    // h A-frag reader: row=l15, k-range s*32+lg*8 (runtime s legal: LDS address)
    auto read_h = [&](int s) -> s16x8 {
        int boff = (l15 * 1024 + s * 64 + lg * 16) ^ ((l15 & 7) << 4);
        return *(const s16x8*)(hw + (boff >> 1));
    };

    // ---- LoRA2 v = h @ A2cat (tiles 16,17), band-mask -> vfrag ----
    s16x8 vfrag;
    {
        for (int i = 0; i < 2; ++i) {
            int t2 = 16 + ((i + w) & 1);
            f32x4 acc = {0.f, 0.f, 0.f, 0.f};
#pragma unroll
            for (int s = 0; s < 16; ++s) {
                int ss = (s + rotw) & 15;
                s16x8 b = *(const s16x8*)(w2base + ((size_t)t2 * 16 + ss) * 512 + lane * 8);
                acc = __builtin_amdgcn_mfma_f32_16x16x32_bf16(read_h(ss), b, acc, 0, 0, 0);
            }
            int colbase = (t2 - 16) * 16 + l15;
#pragma unroll
            for (int r = 0; r < 4; ++r) {
                int row = lg * 4 + r;
                float v = ((colbase >> 3) == s_band[w][row]) ? acc[r] : 0.f;
                scw[row * 40 + colbase] = f2bf(v);
            }
        }
        asm volatile("s_waitcnt lgkmcnt(0)" ::: "memory");
        __builtin_amdgcn_sched_barrier(0);
        vfrag = *(const s16x8*)&scw[l15 * 40 + lg * 8];
    }

    // ---- layer 2: rotated tiles + scatter ----
    float g4[4];
    int tok4[4];
#pragma unroll
    for (int r = 0; r < 4; ++r) {
        int row = lg * 4 + r;
        g4[r] = s_g[w][row];
        tok4[r] = s_tok[w][row];
    }
    for (int i = 0; i < 16; ++i) {
        int t2 = (i + rotw) & 15;
        float bv = b2[(size_t)e * DOUT + t2 * 16 + l15];
        f32x4 acc = {bv, bv, bv, bv};
#pragma unroll
        for (int s = 0; s < 16; ++s) {
            int ss = (s + rotw) & 15;
            s16x8 b = *(const s16x8*)(w2base + ((size_t)t2 * 16 + ss) * 512 + lane * 8);
            acc = __builtin_amdgcn_mfma_f32_16x16x32_bf16(read_h(ss), b, acc, 0, 0, 0);
        }
        {
            s16x8 b = *(const s16x8*)(b2base + (size_t)t2 * 512 + lane * 8);
            acc = __builtin_amdgcn_mfma_f32_16x16x32_bf16(vfrag, b, acc, 0, 0, 0);
        }
        int col = t2 * 16 + l15;
#pragma unroll
        for (int r = 0; r < 4; ++r) {
            atomicAdd(&y[(size_t)tok4[r] * DOUT + col], g4[r] * acc[r]);
        }
    }
}

extern "C" void kernel_launch(void* const* d_in, const int* in_sizes, int n_in,
                              void* d_out, int out_size, void* d_ws, size_t ws_size,
                              hipStream_t stream) {
    const float* x = (const float*)d_in[0];
    const int* band = (const int*)d_in[1];
    const float* Wdct = (const float*)d_in[2];
    const float* Wgate = (const float*)d_in[3];
    const float* W1 = (const float*)d_in[4];
    const float* b1 = (const float*)d_in[5];
    const float* A1 = (const float*)d_in[6];
    const float* B1 = (const float*)d_in[7];
    const float* W2 = (const float*)d_in[8];
    const float* b2 = (const float*)d_in[9];
    const float* A2 = (const float*)d_in[10];
    const float* B2 = (const float*)d_in[11];
    float* y = (float*)d_out;

    float* ws = (float*)d_ws;
    float* logitsT = ws;                          // 524288 words
    unsigned* hist = (unsigned*)(ws + 524288);    // 8192 words
    unsigned* meta = (unsigned*)(ws + 532480);    // 64 words
    float* colsum = ws + 532544;                  // 8
    float* partials = ws + 532552;                // 1024
    int* idxbuf = (int*)(ws + 533576);            // 81920
    int* ties = (int*)(ws + 615496);              // 524288 (ends 1139784)
    ushort* pk = (ushort*)(ws + PK_F32_OFF);      // 2629632 bf16 = 5.26 MB

    hipMemsetAsync(d_out, 0, (size_t)NTOK * DOUT * sizeof(float), stream);
    hipMemsetAsync(hist, 0, (8192 + 64) * sizeof(unsigned), stream);

    k_prep<<<(PK_TOTAL + 255) / 256, 256, 0, stream>>>(W1, A1, B1, W2, A2, B2, pk);
    k_gating<<<NTOK / 256, 256, 0, stream>>>(x, Wdct, Wgate, logitsT, meta);
    k_colsum_part<<<dim3(128, NEXP), 256, 0, stream>>>(logitsT, meta, partials);
    k_colsum_final<<<NEXP, 128, 0, stream>>>(partials, colsum);
    for (int p = 0; p < 4; ++p) {
        k_hist<<<dim3(64, NEXP), 256, 0, stream>>>(logitsT, hist, meta, p);
        k_scan2<<<NEXP, 256, 0, stream>>>(hist, meta, p);
    }
    k_select<<<dim3(64, NEXP), 256, 0, stream>>>(logitsT, meta, &meta[32], idxbuf, ties);
    k_ties<<<NEXP, 256, 0, stream>>>(meta, idxbuf, ties);
    k_expert<<<NEXP * TILES_PER_E, 128, 0, stream>>>(x, band, b1, b2, pk,
                                                     logitsT, meta, colsum, idxbuf, y);
}

// Round 5
// 430.018 us; speedup vs baseline: 2.6788x; 1.1255x over previous
//
#include <hip/hip_runtime.h>
#include <hip/hip_bf16.h>
#include <math.h>

#define NTOK 65536
#define DIN 256
#define DOUT 256
#define HID 512
#define NEXP 8
#define NBAND 4
#define RANK 8
#define CAP 10240
#define NTILE 64
#define TILES_PER_E (CAP / NTILE)  // 160

// packed bf16 weight region (ushort elements), offsets in elements
#define W1CAT_PER_E (34 * 9 * 512)            // 156672
#define B1CAT_OFF   (NEXP * W1CAT_PER_E)      // 1253376
#define B1CAT_PER_E (32 * 512)                // 16384
#define W2CAT_OFF   (B1CAT_OFF + NEXP * B1CAT_PER_E)  // 1384448
#define W2CAT_PER_E (18 * 16 * 512)           // 147456
#define B2CAT_OFF   (W2CAT_OFF + NEXP * W2CAT_PER_E)  // 2564096
#define B2CAT_PER_E (16 * 512)                // 8192
#define PK_TOTAL    (B2CAT_OFF + NEXP * B2CAT_PER_E)  // 2629632
#define PK_F32_OFF  1200000                   // f32-word offset of packed region in ws

typedef short s16x8 __attribute__((ext_vector_type(8)));
typedef float f32x4 __attribute__((ext_vector_type(4)));

__device__ __forceinline__ unsigned key_of(float f) {
    unsigned u = __float_as_uint(f);
    return (u & 0x80000000u) ? ~u : (u | 0x80000000u);
}
__device__ __forceinline__ float gelu_tanh(float v) {
    const float c = 0.7978845608028654f;
    float t = tanhf(c * (v + 0.044715f * v * v * v));
    return 0.5f * v * (1.0f + t);
}
__device__ __forceinline__ ushort f2bf(float f) {  // RNE f32->bf16
    unsigned u = __float_as_uint(f);
    return (ushort)((u + 0x7FFFu + ((u >> 16) & 1u)) >> 16);
}

// ---------------- gating: logitsT[e][n] + fused per-expert exp-partials -----
__global__ __launch_bounds__(256) void k_gating(const float* __restrict__ x,
                                                const float* __restrict__ Wdct,
                                                const float* __restrict__ Wgate,
                                                float* __restrict__ logitsT,
                                                float* __restrict__ partials) {
    __shared__ float xs[256][33];
    __shared__ float wd[32][64];
    __shared__ float wg[320][8];
    __shared__ float pr[4][8];
    int tid = threadIdx.x;
    int n0 = blockIdx.x * 256;
    for (int i = tid; i < 320 * 8; i += 256) ((float*)wg)[i] = Wgate[i];
    float freq[64];
#pragma unroll
    for (int f = 0; f < 64; ++f) freq[f] = 0.f;
    float lg[8];
#pragma unroll
    for (int e = 0; e < 8; ++e) lg[e] = 0.f;
    for (int c = 0; c < 8; ++c) {
        __syncthreads();
        {
            int col = tid & 31, rbase = tid >> 5;
#pragma unroll
            for (int i = 0; i < 32; ++i) {
                int row = i * 8 + rbase;
                xs[row][col] = x[(size_t)(n0 + row) * DIN + c * 32 + col];
            }
        }
        for (int i = tid; i < 2048; i += 256)
            wd[i >> 6][i & 63] = Wdct[(size_t)(c * 32 + (i >> 6)) * 64 + (i & 63)];
        __syncthreads();
        for (int d = 0; d < 32; ++d) {
            float xv = xs[tid][d];
#pragma unroll
            for (int f = 0; f < 64; ++f) freq[f] += xv * wd[d][f];
#pragma unroll
            for (int e = 0; e < 8; ++e) lg[e] += xv * wg[c * 32 + d][e];
        }
    }
#pragma unroll
    for (int f = 0; f < 64; ++f) {
#pragma unroll
        for (int e = 0; e < 8; ++e) lg[e] += freq[f] * wg[256 + f][e];
    }
    int n = n0 + tid;
#pragma unroll
    for (int e = 0; e < 8; ++e) logitsT[(size_t)e * NTOK + n] = lg[e];
    // per-expert block partial of sum(exp(l))  (no max subtraction needed:
    // logits are O(+-2), exp is safe; g = exp(l)/S identical to softmax)
    int wv = tid >> 6, lane = tid & 63;
#pragma unroll
    for (int e = 0; e < 8; ++e) {
        float v = expf(lg[e]);
#pragma unroll
        for (int off = 32; off > 0; off >>= 1) v += __shfl_xor(v, off);
        if (lane == 0) pr[wv][e] = v;
    }
    __syncthreads();
    if (tid < 8) partials[tid * 256 + blockIdx.x] =
        pr[0][tid] + pr[1][tid] + pr[2][tid] + pr[3][tid];
}

// ---------------- single-kernel top-CAP select (per-expert block) -----------
// block e: colsum finalize + 4 radix passes + scan + select + ties, all local.
__global__ __launch_bounds__(1024) void k_topk(const float* __restrict__ logitsT,
                                               const float* __restrict__ partials,
                                               float* __restrict__ colsum,
                                               int* __restrict__ idxbuf) {
    __shared__ unsigned subh[16][257];
    __shared__ unsigned bins[256];
    __shared__ float ssum[16];
    __shared__ unsigned sval[2];   // pref, rem
    __shared__ unsigned scnt, stcnt;
    __shared__ int ties_l[2048];
    int e = blockIdx.x, tid = threadIdx.x, w = tid >> 6, lane = tid & 63;
    const float* lp = logitsT + (size_t)e * NTOK;

    // ---- colsum finalize ----
    {
        float s = (tid < 256) ? partials[e * 256 + tid] : 0.f;
#pragma unroll
        for (int off = 32; off > 0; off >>= 1) s += __shfl_xor(s, off);
        if (lane == 0 && w < 4) ssum[w] = s;
        __syncthreads();
        if (tid == 0) colsum[e] = ssum[0] + ssum[1] + ssum[2] + ssum[3];
    }

    // ---- 4-pass radix select over ordered uint keys ----
    unsigned pref = 0, rem = CAP;
    for (int p = 0; p < 4; ++p) {
        int shift = 24 - 8 * p;
        for (int i = tid; i < 16 * 257; i += 1024) ((unsigned*)subh)[i] = 0;
        __syncthreads();
        for (int it = 0; it < 64; ++it) {
            int n = it * 1024 + tid;
            unsigned k = key_of(lp[n]);
            bool ok = (p == 0) || ((k >> (shift + 8)) == pref);
            if (ok) atomicAdd(&subh[w][(k >> shift) & 255u], 1u);
        }
        __syncthreads();
        if (tid < 256) {
            unsigned c = 0;
#pragma unroll
            for (int ww = 0; ww < 16; ++ww) c += subh[ww][tid];
            bins[tid] = c;
        }
        __syncthreads();
        for (int off = 1; off < 256; off <<= 1) {
            unsigned add = (tid < 256 && tid + off < 256) ? bins[tid + off] : 0u;
            __syncthreads();
            if (tid < 256) bins[tid] += add;
            __syncthreads();
        }
        if (tid < 256) {
            unsigned snext = (tid == 255) ? 0u : bins[tid + 1];
            if (bins[tid] >= rem && snext < rem) {
                sval[0] = (pref << 8) | (unsigned)tid;
                sval[1] = rem - snext;
            }
        }
        __syncthreads();
        pref = sval[0];
        rem = sval[1];
        __syncthreads();
    }

    // ---- select + tie placement ----
    if (tid == 0) { scnt = 0; stcnt = 0; }
    __syncthreads();
    unsigned T = pref;
    for (int it = 0; it < 64; ++it) {
        int n = it * 1024 + tid;
        unsigned k = key_of(lp[n]);
        if (k > T) {
            unsigned pos = atomicAdd(&scnt, 1u);
            idxbuf[e * CAP + pos] = n;
        } else if (k == T) {
            unsigned tp = atomicAdd(&stcnt, 1u);
            if (tp < 2048) ties_l[tp] = n;
        }
    }
    __syncthreads();
    int m = (int)stcnt, r = (int)rem, base = CAP - r;
    if (m == r) {
        for (int i = tid; i < m; i += 1024) idxbuf[e * CAP + base + i] = ties_l[i];
    } else {
        for (int i = tid; i < m; i += 1024) {
            int my = ties_l[i];
            int rank = 0;
            for (int j = 0; j < m; ++j) rank += (ties_l[j] < my);
            if (rank < r) idxbuf[e * CAP + base + rank] = my;
        }
    }
}

// ---------------- weight packing into MFMA fragment order (bf16) ------------
__global__ __launch_bounds__(256) void k_prep(const float* __restrict__ W1,
                                              const float* __restrict__ A1,
                                              const float* __restrict__ B1,
                                              const float* __restrict__ W2,
                                              const float* __restrict__ A2,
                                              const float* __restrict__ B2,
                                              ushort* __restrict__ pk) {
    int id = blockIdx.x * 256 + threadIdx.x;
    if (id >= PK_TOTAL) return;
    float val;
    if (id < B1CAT_OFF) {
        int e = id / W1CAT_PER_E, rem = id % W1CAT_PER_E;
        int t = rem / (9 * 512); rem %= 9 * 512;
        int s = rem / 512; int q = rem & 511;
        int l = q >> 3, j = q & 7;
        int k = s * 32 + ((l >> 4) << 3) + j;
        int col = t * 16 + (l & 15);
        if (k > 256) val = 0.f;
        else if (col < 512) val = W1[((size_t)e * 257 + k) * 512 + col];
        else {
            int cu = col - 512;
            val = A1[(((size_t)e * NBAND + (cu >> 3)) * 257 + k) * RANK + (cu & 7)];
        }
    } else if (id < W2CAT_OFF) {
        int id2 = id - B1CAT_OFF;
        int e = id2 / B1CAT_PER_E, rem = id2 % B1CAT_PER_E;
        int t = rem / 512; int q = rem & 511;
        int l = q >> 3, j = q & 7;
        int k32 = ((l >> 4) << 3) + j;
        int col = t * 16 + (l & 15);
        val = 2.0f * B1[(((size_t)e * NBAND + (k32 >> 3)) * RANK + (k32 & 7)) * 512 + col];
    } else if (id < B2CAT_OFF) {
        int id2 = id - W2CAT_OFF;
        int e = id2 / W2CAT_PER_E, rem = id2 % W2CAT_PER_E;
        int t = rem / (16 * 512); rem %= 16 * 512;
        int s = rem / 512; int q = rem & 511;
        int l = q >> 3, j = q & 7;
        int k = s * 32 + ((l >> 4) << 3) + j;
        int col = t * 16 + (l & 15);
        if (col < 256) val = W2[((size_t)e * 512 + k) * 256 + col];
        else {
            int cv = col - 256;
            val = A2[(((size_t)e * NBAND + (cv >> 3)) * 512 + k) * RANK + (cv & 7)];
        }
    } else {
        int id2 = id - B2CAT_OFF;
        int e = id2 / B2CAT_PER_E, rem = id2 % B2CAT_PER_E;
        int t = rem / 512; int q = rem & 511;
        int l = q >> 3, j = q & 7;
        int k32 = ((l >> 4) << 3) + j;
        int col = t * 16 + (l & 15);
        val = 2.0f * B2[(((size_t)e * NBAND + (k32 >> 3)) * RANK + (k32 & 7)) * 256 + col];
    }
    pk[id] = f2bf(val);
}

// ---------------- fused expert MLP (MFMA, layer1<->layer2 pipelined) --------
// 4 waves/block, each wave 16 tokens. e=bid&7 == XCD id (round-robin dispatch)
// so every CU runs exactly one expert; waves kept lockstep for L1 reuse.
__global__ __launch_bounds__(256, 2) void k_expert(
    const float* __restrict__ x, const int* __restrict__ band,
    const float* __restrict__ b1, const float* __restrict__ b2,
    const ushort* __restrict__ pk,
    const float* __restrict__ logitsT,
    const float* __restrict__ colsum, const int* __restrict__ idxbuf,
    float* __restrict__ y) {
    __shared__ ushort sc[4][16 * 40];   // per-wave transpose scratch
    __shared__ int s_tok[4][16];
    __shared__ int s_band[4][16];
    __shared__ float s_g[4][16];

    int tid = threadIdx.x, w = tid >> 6, lane = tid & 63;
    int bid = blockIdx.x;
    int e = bid & 7;            // XCD-pinned expert
    int tile = bid >> 3;        // 0..159

    if (lane < 16) {
        int n = idxbuf[e * CAP + tile * NTILE + w * 16 + lane];
        s_tok[w][lane] = n;
        s_band[w][lane] = band[n];
        s_g[w][lane] = expf(logitsT[(size_t)e * NTOK + n]) / colsum[e];
    }
    __syncthreads();

    int l15 = lane & 15, lg = lane >> 4;
    ushort* scw = &sc[w][0];

    // ---- A-frags for layer 1 (K=288: 9 ksteps) ----
    s16x8 a1[9];
    {
        int mytok = s_tok[w][l15];
        const float* xrow = x + (size_t)mytok * DIN;
        int kg = lg << 3;
#pragma unroll
        for (int s = 0; s < 8; ++s) {
            float4 p = *(const float4*)&xrow[s * 32 + kg];
            float4 q = *(const float4*)&xrow[s * 32 + kg + 4];
            s16x8 a;
            a[0] = (short)f2bf(p.x); a[1] = (short)f2bf(p.y);
            a[2] = (short)f2bf(p.z); a[3] = (short)f2bf(p.w);
            a[4] = (short)f2bf(q.x); a[5] = (short)f2bf(q.y);
            a[6] = (short)f2bf(q.z); a[7] = (short)f2bf(q.w);
            a1[s] = a;
        }
        s16x8 a = (s16x8)(short)0;
        if (lane < 16) a[0] = (short)f2bf((float)s_band[w][l15] * 0.25f);
        a1[8] = a;
    }

    const ushort* w1base = pk + (size_t)e * W1CAT_PER_E;
    const ushort* b1base = pk + B1CAT_OFF + (size_t)e * B1CAT_PER_E;
    const ushort* w2base = pk + W2CAT_OFF + (size_t)e * W2CAT_PER_E;
    const ushort* b2base = pk + B2CAT_OFF + (size_t)e * B2CAT_PER_E;

    // ---- LoRA1 u = xe @ A1cat (tiles 32,33), band-mask -> ufrag ----
    s16x8 ufrag;
    {
#pragma unroll
        for (int t = 32; t <= 33; ++t) {
            f32x4 acc = {0.f, 0.f, 0.f, 0.f};
#pragma unroll
            for (int s = 0; s < 9; ++s) {
                s16x8 b = *(const s16x8*)(w1base + ((size_t)t * 9 + s) * 512 + lane * 8);
                acc = __builtin_amdgcn_mfma_f32_16x16x32_bf16(a1[s], b, acc, 0, 0, 0);
            }
            int colbase = (t - 32) * 16 + l15;
#pragma unroll
            for (int r = 0; r < 4; ++r) {
                int row = lg * 4 + r;
                float v = ((colbase >> 3) == s_band[w][row]) ? acc[r] : 0.f;
                scw[row * 40 + colbase] = f2bf(v);
            }
        }
        asm volatile("s_waitcnt lgkmcnt(0)" ::: "memory");
        __builtin_amdgcn_sched_barrier(0);
        ufrag = *(const s16x8*)&scw[l15 * 40 + lg * 8];
    }

    // ---- layer2 accumulators (bias-initialized), LoRA2 accumulators ----
    f32x4 oacc[16];
#pragma unroll
    for (int t2 = 0; t2 < 16; ++t2) {
        float bv = b2[(size_t)e * DOUT + t2 * 16 + l15];
        oacc[t2] = (f32x4){bv, bv, bv, bv};
    }
    f32x4 vacc[2];
    vacc[0] = (f32x4){0.f, 0.f, 0.f, 0.f};
    vacc[1] = (f32x4){0.f, 0.f, 0.f, 0.f};

    // ---- main loop: 16 h-chunks of 32; produce then immediately consume ----
    for (int p = 0; p < 16; ++p) {
        // layer 1: two 16-col tiles -> gelu -> scratch (D->A transpose)
#pragma unroll
        for (int half = 0; half < 2; ++half) {
            int t = p * 2 + half;
            float bv = b1[(size_t)e * HID + t * 16 + l15];
            f32x4 acc = {bv, bv, bv, bv};
#pragma unroll
            for (int s = 0; s < 9; ++s) {
                s16x8 b = *(const s16x8*)(w1base + ((size_t)t * 9 + s) * 512 + lane * 8);
                acc = __builtin_amdgcn_mfma_f32_16x16x32_bf16(a1[s], b, acc, 0, 0, 0);
            }
            {
                s16x8 b = *(const s16x8*)(b1base + (size_t)t * 512 + lane * 8);
                acc = __builtin_amdgcn_mfma_f32_16x16x32_bf16(ufrag, b, acc, 0, 0, 0);
            }
#pragma unroll
            for (int r = 0; r < 4; ++r) {
                int row = lg * 4 + r;
                scw[row * 40 + half * 16 + l15] = f2bf(gelu_tanh(acc[r]));
            }
        }
        asm volatile("s_waitcnt lgkmcnt(0)" ::: "memory");
        __builtin_amdgcn_sched_barrier(0);
        s16x8 hfrag = *(const s16x8*)&scw[l15 * 40 + lg * 8];

        // layer 2 partial: 16 independent output-tile accs + 2 LoRA2 accs
#pragma unroll
        for (int t2 = 0; t2 < 16; ++t2) {
            s16x8 b = *(const s16x8*)(w2base + ((size_t)t2 * 16 + p) * 512 + lane * 8);
            oacc[t2] = __builtin_amdgcn_mfma_f32_16x16x32_bf16(hfrag, b, oacc[t2], 0, 0, 0);
        }
#pragma unroll
        for (int i = 0; i < 2; ++i) {
            s16x8 b = *(const s16x8*)(w2base + ((size_t)(16 + i) * 16 + p) * 512 + lane * 8);
            vacc[i] = __builtin_amdgcn_mfma_f32_16x16x32_bf16(hfrag, b, vacc[i], 0, 0, 0);
        }
        __syncthreads();   // lockstep waves (L1 reuse) + guards scw reuse
    }

    // ---- LoRA2: band-mask v, transpose -> vfrag, fold through B2cat ----
    s16x8 vfrag;
    {
#pragma unroll
        for (int i = 0; i < 2; ++i) {
            int colbase = i * 16 + l15;
#pragma unroll
            for (int r = 0; r < 4; ++r) {
                int row = lg * 4 + r;
                float v = ((colbase >> 3) == s_band[w][row]) ? vacc[i][r] : 0.f;
                scw[row * 40 + colbase] = f2bf(v);
            }
        }
        asm volatile("s_waitcnt lgkmcnt(0)" ::: "memory");
        __builtin_amdgcn_sched_barrier(0);
        vfrag = *(const s16x8*)&scw[l15 * 40 + lg * 8];
    }

    float g4[4];
    int tok4[4];
#pragma unroll
    for (int r = 0; r < 4; ++r) {
        int row = lg * 4 + r;
        g4[r] = s_g[w][row];
        tok4[r] = s_tok[w][row];
    }
#pragma unroll
    for (int t2 = 0; t2 < 16; ++t2) {
        s16x8 b = *(const s16x8*)(b2base + (size_t)t2 * 512 + lane * 8);
        f32x4 acc = __builtin_amdgcn_mfma_f32_16x16x32_bf16(vfrag, b, oacc[t2], 0, 0, 0);
        int col = t2 * 16 + l15;
#pragma unroll
        for (int r = 0; r < 4; ++r) {
            atomicAdd(&y[(size_t)tok4[r] * DOUT + col], g4[r] * acc[r]);
        }
    }
}

extern "C" void kernel_launch(void* const* d_in, const int* in_sizes, int n_in,
                              void* d_out, int out_size, void* d_ws, size_t ws_size,
                              hipStream_t stream) {
    const float* x = (const float*)d_in[0];
    const int* band = (const int*)d_in[1];
    const float* Wdct = (const float*)d_in[2];
    const float* Wgate = (const float*)d_in[3];
    const float* W1 = (const float*)d_in[4];
    const float* b1 = (const float*)d_in[5];
    const float* A1 = (const float*)d_in[6];
    const float* B1 = (const float*)d_in[7];
    const float* W2 = (const float*)d_in[8];
    const float* b2 = (const float*)d_in[9];
    const float* A2 = (const float*)d_in[10];
    const float* B2 = (const float*)d_in[11];
    float* y = (float*)d_out;

    float* ws = (float*)d_ws;
    float* logitsT = ws;                          // 524288 words
    float* partials = ws + 524288;                // 2048
    float* colsum = ws + 526336;                  // 8
    int* idxbuf = (int*)(ws + 526352);            // 81920 (ends 608272)
    ushort* pk = (ushort*)(ws + PK_F32_OFF);      // 2629632 bf16 = 5.26 MB

    hipMemsetAsync(d_out, 0, (size_t)NTOK * DOUT * sizeof(float), stream);

    k_prep<<<(PK_TOTAL + 255) / 256, 256, 0, stream>>>(W1, A1, B1, W2, A2, B2, pk);
    k_gating<<<NTOK / 256, 256, 0, stream>>>(x, Wdct, Wgate, logitsT, partials);
    k_topk<<<NEXP, 1024, 0, stream>>>(logitsT, partials, colsum, idxbuf);
    k_expert<<<NEXP * TILES_PER_E, 256, 0, stream>>>(x, band, b1, b2, pk,
                                                     logitsT, colsum, idxbuf, y);
}